// Round 1
// baseline (228.084 us; speedup 1.0000x reference)
//
#include <hip/hip_runtime.h>
#include <math.h>

// LightConv1d: B=8, C=1024, T=4096, H=16, K=7, causal pad L=6.
// out[b,c,t] = sum_k softmax(w)[c%16,k] * x[b,c,t-6+k] + bias[c%16]
#define TT 4096
#define KK 7
#define HH 16

__global__ void softmax_w_kernel(const float* __restrict__ w,
                                 float* __restrict__ wsm) {
    int h = threadIdx.x;
    if (h < HH) {
        float v[KK];
        float m = -1e30f;
        #pragma unroll
        for (int k = 0; k < KK; ++k) { v[k] = w[h * KK + k]; m = fmaxf(m, v[k]); }
        float s = 0.f;
        #pragma unroll
        for (int k = 0; k < KK; ++k) { v[k] = expf(v[k] - m); s += v[k]; }
        float inv = 1.f / s;
        #pragma unroll
        for (int k = 0; k < KK; ++k) wsm[h * KK + k] = v[k] * inv;
    }
}

__global__ __launch_bounds__(256) void lightconv_kernel(
    const float* __restrict__ x, const float* __restrict__ wsm,
    const float* __restrict__ bias, float* __restrict__ out) {
    const int Q   = blockIdx.x * 256 + threadIdx.x;  // global quad (float4) index
    const int row = Q >> 10;        // b*C + c   (T/4 = 1024 quads per row)
    const int tq  = Q & 1023;       // quad within row
    const int h   = row & (HH - 1); // wave-uniform (1024 % 64 == 0)

    // softmax'd weights + bias: wave-uniform h -> scalar loads, L1/L2 cached
    const float w0 = wsm[h * KK + 0], w1 = wsm[h * KK + 1], w2 = wsm[h * KK + 2],
                w3 = wsm[h * KK + 3], w4 = wsm[h * KK + 4], w5 = wsm[h * KK + 5],
                w6 = wsm[h * KK + 6];
    const float bb = bias[h];

    const float4* xr = (const float4*)(x + (size_t)row * TT);
    float4 q2 = xr[tq];                       // x[t0 .. t0+3]
    float4 q1 = make_float4(0.f, 0.f, 0.f, 0.f);
    float4 q0 = make_float4(0.f, 0.f, 0.f, 0.f);
    if (tq >= 1) q1 = xr[tq - 1];             // x[t0-4 .. t0-1]
    if (tq >= 2) q0 = xr[tq - 2];             // x[t0-8 .. t0-5]

    // f[i] = x[t0 - 8 + i]; out[t0+j] = sum_k w[k]*x[t0+j-6+k] = sum_k w[k]*f[j+k+2]
    float f[12] = {q0.x, q0.y, q0.z, q0.w,
                   q1.x, q1.y, q1.z, q1.w,
                   q2.x, q2.y, q2.z, q2.w};

    float4 o;
    float* op = &o.x;
    #pragma unroll
    for (int j = 0; j < 4; ++j) {
        float acc = bb;
        acc = fmaf(w0, f[j + 2], acc);
        acc = fmaf(w1, f[j + 3], acc);
        acc = fmaf(w2, f[j + 4], acc);
        acc = fmaf(w3, f[j + 5], acc);
        acc = fmaf(w4, f[j + 6], acc);
        acc = fmaf(w5, f[j + 7], acc);
        acc = fmaf(w6, f[j + 8], acc);
        op[j] = acc;
    }
    ((float4*)(out + (size_t)row * TT))[tq] = o;
}

extern "C" void kernel_launch(void* const* d_in, const int* in_sizes, int n_in,
                              void* d_out, int out_size, void* d_ws, size_t ws_size,
                              hipStream_t stream) {
    const float* x    = (const float*)d_in[0];
    const float* w    = (const float*)d_in[1];
    const float* bias = (const float*)d_in[2];
    float* out = (float*)d_out;
    float* wsm = (float*)d_ws;  // 16*7 floats, rewritten every call (ws is re-poisoned)

    softmax_w_kernel<<<1, 64, 0, stream>>>(w, wsm);

    const int totalQ = out_size / 4;           // 8,388,608 float4s
    lightconv_kernel<<<totalQ / 256, 256, 0, stream>>>(x, wsm, bias, out);
}